// Round 5
// baseline (231.021 us; speedup 1.0000x reference)
//
#include <hip/hip_runtime.h>

// SoftAttention: B=4, Q=64, S=1024, H=512, fp32.
// out = [context (B*Q*H)] ++ [weights (B*Q*S)]
// ws: qp [256*512] at 0; kp [4096*512] at +512KB.
// Pipeline: init (qp/kp=2*bias, ctx=0) -> proj (split-K=2, atomicAdd 2*acc)
//   -> score (raw) -> softmax (in place) -> context (atomicAdd into ctx).
// qp/kp hold 2*(X@W+b); score uses exp(2*(q+k)); be cancels in softmax.

constexpr int kB = 4;
constexpr int kQ = 64;
constexpr int kS = 1024;
constexpr int kH = 512;

// ---------------------------------------------------------------------------
// Init: kp rows = 2*bk, qp rows = 2*bq, ctx = 0.
// ---------------------------------------------------------------------------
constexpr int kKpF4 = kB * kS * kH / 4;   // 524288
constexpr int kQpF4 = kB * kQ * kH / 4;   // 32768
constexpr int kCtxF4 = kB * kQ * kH / 4;  // 32768

__global__ __launch_bounds__(256) void init_kernel(
    const float* __restrict__ bk, const float* __restrict__ bq,
    float* __restrict__ kp, float* __restrict__ qp, float* __restrict__ ctx) {
  const int i = blockIdx.x * 256 + threadIdx.x;
  const int colmask = kH / 4 - 1;
  if (i < kKpF4) {
    float4 v = ((const float4*)bk)[i & colmask];
    v.x *= 2.f; v.y *= 2.f; v.z *= 2.f; v.w *= 2.f;
    ((float4*)kp)[i] = v;
  } else if (i < kKpF4 + kQpF4) {
    const int j = i - kKpF4;
    float4 v = ((const float4*)bq)[j & colmask];
    v.x *= 2.f; v.y *= 2.f; v.z *= 2.f; v.w *= 2.f;
    ((float4*)qp)[j] = v;
  } else if (i < kKpF4 + kQpF4 + kCtxF4) {
    float4 z = {0.f, 0.f, 0.f, 0.f};
    ((float4*)ctx)[i - kKpF4 - kQpF4] = z;
  }
}

// ---------------------------------------------------------------------------
// Projection: atomically adds 2*(X_tile @ W_ktile) into Y.
// 64x64 tile, 256 thr, 4x4 acc/thread, K-chunks of 32 double-buffered.
// grid = (8 col-tiles, 68 row-tiles [64 kp + 4 qp], 2 K-halves of 256)
// ---------------------------------------------------------------------------
constexpr int kLdsStride = 68;

__global__ __launch_bounds__(256, 4) void proj_dual(
    const float* __restrict__ Xk, const float* __restrict__ Wk,
    float* __restrict__ Yk,
    const float* __restrict__ Xq, const float* __restrict__ Wq,
    float* __restrict__ Yq) {
  __shared__ __align__(16) float As[2][32 * kLdsStride];  // [k][row]
  __shared__ __align__(16) float Bs[2][32 * kLdsStride];  // [k][col]
  const int t = threadIdx.x;
  const int ct = blockIdx.x;          // 0..7
  int rt = blockIdx.y;                // 0..67
  const int kz = blockIdx.z * 256;    // K half base
  const float *X, *W;
  float* Y;
  if (rt < 64) {
    X = Xk + (size_t)rt * 64 * kH; W = Wk; Y = Yk + (size_t)rt * 64 * kH;
  } else {
    rt -= 64;
    X = Xq + (size_t)rt * 64 * kH; W = Wq; Y = Yq + (size_t)rt * 64 * kH;
  }

  const int a_row = t & 63;
  const int a_k0 = (t >> 6) * 8;
  const int b_kl = t >> 4;
  const int b_c = (t & 15) * 4;
  const int cbase = ct * 64;
  const int r0 = (t >> 4) * 4;
  const int c0 = (t & 15) * 4;

  float4 pa[2], pb[2];

  auto gload = [&](int kb) {
    const float* xp = X + (size_t)a_row * kH + kb + a_k0;
    pa[0] = *(const float4*)(xp + 0);
    pa[1] = *(const float4*)(xp + 4);
#pragma unroll
    for (int p = 0; p < 2; p++)
      pb[p] = *(const float4*)(W + (size_t)(kb + p * 16 + b_kl) * kH + cbase + b_c);
  };

  auto lwrite = [&](int buf) {
    float* a = As[buf];
#pragma unroll
    for (int j = 0; j < 2; j++) {
      a[(a_k0 + 4 * j + 0) * kLdsStride + a_row] = pa[j].x;
      a[(a_k0 + 4 * j + 1) * kLdsStride + a_row] = pa[j].y;
      a[(a_k0 + 4 * j + 2) * kLdsStride + a_row] = pa[j].z;
      a[(a_k0 + 4 * j + 3) * kLdsStride + a_row] = pa[j].w;
    }
    float* b = Bs[buf];
#pragma unroll
    for (int p = 0; p < 2; p++)
      *(float4*)(b + (p * 16 + b_kl) * kLdsStride + b_c) = pb[p];
  };

  float4 acc0 = {0,0,0,0}, acc1 = {0,0,0,0}, acc2 = {0,0,0,0}, acc3 = {0,0,0,0};

  gload(kz);
  lwrite(0);
  __syncthreads();

  for (int kc = 0; kc < 8; kc++) {
    if (kc < 7) gload(kz + (kc + 1) * 32);

    const float* a = As[kc & 1];
    const float* b = Bs[kc & 1];
#pragma unroll 8
    for (int kk = 0; kk < 32; kk++) {
      float4 av = *(const float4*)(a + kk * kLdsStride + r0);
      float4 bv = *(const float4*)(b + kk * kLdsStride + c0);
      acc0.x = fmaf(av.x, bv.x, acc0.x); acc0.y = fmaf(av.x, bv.y, acc0.y);
      acc0.z = fmaf(av.x, bv.z, acc0.z); acc0.w = fmaf(av.x, bv.w, acc0.w);
      acc1.x = fmaf(av.y, bv.x, acc1.x); acc1.y = fmaf(av.y, bv.y, acc1.y);
      acc1.z = fmaf(av.y, bv.z, acc1.z); acc1.w = fmaf(av.y, bv.w, acc1.w);
      acc2.x = fmaf(av.z, bv.x, acc2.x); acc2.y = fmaf(av.z, bv.y, acc2.y);
      acc2.z = fmaf(av.z, bv.z, acc2.z); acc2.w = fmaf(av.z, bv.w, acc2.w);
      acc3.x = fmaf(av.w, bv.x, acc3.x); acc3.y = fmaf(av.w, bv.y, acc3.y);
      acc3.z = fmaf(av.w, bv.z, acc3.z); acc3.w = fmaf(av.w, bv.w, acc3.w);
    }

    if (kc < 7) {
      __syncthreads();
      lwrite((kc + 1) & 1);
      __syncthreads();
    }
  }

  float* yp = Y + (size_t)r0 * kH + cbase + c0;
  unsafeAtomicAdd(yp + 0 * kH + 0, 2.f * acc0.x);
  unsafeAtomicAdd(yp + 0 * kH + 1, 2.f * acc0.y);
  unsafeAtomicAdd(yp + 0 * kH + 2, 2.f * acc0.z);
  unsafeAtomicAdd(yp + 0 * kH + 3, 2.f * acc0.w);
  unsafeAtomicAdd(yp + 1 * kH + 0, 2.f * acc1.x);
  unsafeAtomicAdd(yp + 1 * kH + 1, 2.f * acc1.y);
  unsafeAtomicAdd(yp + 1 * kH + 2, 2.f * acc1.z);
  unsafeAtomicAdd(yp + 1 * kH + 3, 2.f * acc1.w);
  unsafeAtomicAdd(yp + 2 * kH + 0, 2.f * acc2.x);
  unsafeAtomicAdd(yp + 2 * kH + 1, 2.f * acc2.y);
  unsafeAtomicAdd(yp + 2 * kH + 2, 2.f * acc2.z);
  unsafeAtomicAdd(yp + 2 * kH + 3, 2.f * acc2.w);
  unsafeAtomicAdd(yp + 3 * kH + 0, 2.f * acc3.x);
  unsafeAtomicAdd(yp + 3 * kH + 1, 2.f * acc3.y);
  unsafeAtomicAdd(yp + 3 * kH + 2, 2.f * acc3.z);
  unsafeAtomicAdd(yp + 3 * kH + 3, 2.f * acc3.w);
}

// ---------------------------------------------------------------------------
// Scores (raw) -> sout[bq][s].  tanh(x) = 1 - 2*rcp(1+exp(2x));
// sum we*tanh = sum_we + sum (-2*we)*rcp(1+exp(2q+2k)).
// grid = 1024 (b x 16 q-tiles x 16 s-chunks), 256 thr = 4 waves, 16 s/wave.
// ---------------------------------------------------------------------------
__global__ __launch_bounds__(256) void score_kernel(
    const float* __restrict__ qp, const float* __restrict__ kp,
    const float* __restrict__ we, float* __restrict__ sout) {
  const int bx = blockIdx.x;
  const int b = bx >> 8, qt = (bx >> 4) & 15, st = bx & 15;
  const int t = threadIdx.x, wave = t >> 6, lane = t & 63;

  const float4* we4 = (const float4*)(we + lane * 8);
  float4 w0 = we4[0], w1 = we4[1];
  float wsum = w0.x + w0.y + w0.z + w0.w + w1.x + w1.y + w1.z + w1.w;
#pragma unroll
  for (int off = 32; off; off >>= 1) wsum += __shfl_xor(wsum, off);
  w0.x *= -2.f; w0.y *= -2.f; w0.z *= -2.f; w0.w *= -2.f;
  w1.x *= -2.f; w1.y *= -2.f; w1.z *= -2.f; w1.w *= -2.f;

  const int q0 = qt * 4;
  float4 qv[4][2];
#pragma unroll
  for (int i = 0; i < 4; i++) {
    const float4* q4 = (const float4*)(qp + (size_t)(b * kQ + q0 + i) * kH + lane * 8);
    qv[i][0] = q4[0]; qv[i][1] = q4[1];
  }

  const int sbase = st * 64 + wave * 16;
  const float* kbase = kp + ((size_t)b * kS + sbase) * kH + lane * 8;

  float4 k0 = *(const float4*)(kbase);
  float4 k1 = *(const float4*)(kbase + 4);

  for (int si = 0; si < 16; si++) {
    float4 n0, n1;
    if (si < 15) {
      const float* np = kbase + (size_t)(si + 1) * kH;
      n0 = *(const float4*)(np);
      n1 = *(const float4*)(np + 4);
    }
    float a[4];
#pragma unroll
    for (int i = 0; i < 4; i++) {
      float acc = 0.f, e;
      e = __expf(qv[i][0].x + k0.x); acc = fmaf(w0.x, __builtin_amdgcn_rcpf(1.f + e), acc);
      e = __expf(qv[i][0].y + k0.y); acc = fmaf(w0.y, __builtin_amdgcn_rcpf(1.f + e), acc);
      e = __expf(qv[i][0].z + k0.z); acc = fmaf(w0.z, __builtin_amdgcn_rcpf(1.f + e), acc);
      e = __expf(qv[i][0].w + k0.w); acc = fmaf(w0.w, __builtin_amdgcn_rcpf(1.f + e), acc);
      e = __expf(qv[i][1].x + k1.x); acc = fmaf(w1.x, __builtin_amdgcn_rcpf(1.f + e), acc);
      e = __expf(qv[i][1].y + k1.y); acc = fmaf(w1.y, __builtin_amdgcn_rcpf(1.f + e), acc);
      e = __expf(qv[i][1].z + k1.z); acc = fmaf(w1.z, __builtin_amdgcn_rcpf(1.f + e), acc);
      e = __expf(qv[i][1].w + k1.w); acc = fmaf(w1.w, __builtin_amdgcn_rcpf(1.f + e), acc);
      a[i] = acc;
    }
#pragma unroll
    for (int i = 0; i < 4; i++) {
#pragma unroll
      for (int off = 32; off; off >>= 1) a[i] += __shfl_xor(a[i], off);
    }
    if (lane == 0) {
      const int s = sbase + si;
#pragma unroll
      for (int i = 0; i < 4; i++)
        sout[(size_t)(b * kQ + q0 + i) * kS + s] = a[i] + wsum;
    }
    k0 = n0; k1 = n1;
  }
}

// ---------------------------------------------------------------------------
// Softmax in place on wout rows of 1024.  grid = 256 rows, 256 thr.
// ---------------------------------------------------------------------------
__global__ __launch_bounds__(256) void softmax_kernel(float* __restrict__ wout) {
  __shared__ float redm[4];
  __shared__ float reds[4];
  const int row = blockIdx.x;
  const int t = threadIdx.x, wave = t >> 6, lane = t & 63;
  float4* rp = (float4*)(wout + (size_t)row * kS);
  float4 v = rp[t];

  float m = fmaxf(fmaxf(v.x, v.y), fmaxf(v.z, v.w));
#pragma unroll
  for (int off = 32; off; off >>= 1) m = fmaxf(m, __shfl_xor(m, off));
  if (lane == 0) redm[wave] = m;
  __syncthreads();
  m = fmaxf(fmaxf(redm[0], redm[1]), fmaxf(redm[2], redm[3]));

  float4 e;
  e.x = __expf(v.x - m); e.y = __expf(v.y - m);
  e.z = __expf(v.z - m); e.w = __expf(v.w - m);
  float sum = e.x + e.y + e.z + e.w;
#pragma unroll
  for (int off = 32; off; off >>= 1) sum += __shfl_xor(sum, off);
  if (lane == 0) reds[wave] = sum;
  __syncthreads();
  sum = reds[0] + reds[1] + reds[2] + reds[3];
  float inv = 1.f / sum;
  e.x *= inv; e.y *= inv; e.z *= inv; e.w *= inv;
  rp[t] = e;
}

// ---------------------------------------------------------------------------
// Context: atomicAdd partial sums over a 64-s chunk into ctx.
// grid = 512 (b x 2 h-chunks x 4 q-chunks x 16 s-chunks), 256 thr.
// ---------------------------------------------------------------------------
__global__ __launch_bounds__(256) void context_kernel(
    const float* __restrict__ wout, const float* __restrict__ value,
    float* __restrict__ ctx) {
  __shared__ __align__(16) float wt[64][16];
  const int bx = blockIdx.x;
  const int sc = bx & 15, qc = (bx >> 4) & 3, hc = (bx >> 6) & 1, b = bx >> 7;
  const int t = threadIdx.x;
  const int s0 = sc * 64, q0 = qc * 16;

  {  // load + transpose weights tile [16 q][64 s] -> wt[s][q]
    const int q_l = t & 15;
    const int sseg = (t >> 4) * 4;
    float4 u = *(const float4*)(wout + (size_t)(b * kQ + q0 + q_l) * kS + s0 + sseg);
    wt[sseg + 0][q_l] = u.x; wt[sseg + 1][q_l] = u.y;
    wt[sseg + 2][q_l] = u.z; wt[sseg + 3][q_l] = u.w;
  }
  __syncthreads();

  const int h = hc * 256 + t;
  const float* vb = value + ((size_t)b * kS + s0) * kH + h;
  float acc[16];
#pragma unroll
  for (int i = 0; i < 16; i++) acc[i] = 0.f;

#pragma unroll 8
  for (int s = 0; s < 64; s++) {
    float v = vb[(size_t)s * kH];
    const float4* wrow = (const float4*)&wt[s][0];
    float4 a0 = wrow[0], a1 = wrow[1], a2 = wrow[2], a3 = wrow[3];
    acc[0]  = fmaf(a0.x, v, acc[0]);  acc[1]  = fmaf(a0.y, v, acc[1]);
    acc[2]  = fmaf(a0.z, v, acc[2]);  acc[3]  = fmaf(a0.w, v, acc[3]);
    acc[4]  = fmaf(a1.x, v, acc[4]);  acc[5]  = fmaf(a1.y, v, acc[5]);
    acc[6]  = fmaf(a1.z, v, acc[6]);  acc[7]  = fmaf(a1.w, v, acc[7]);
    acc[8]  = fmaf(a2.x, v, acc[8]);  acc[9]  = fmaf(a2.y, v, acc[9]);
    acc[10] = fmaf(a2.z, v, acc[10]); acc[11] = fmaf(a2.w, v, acc[11]);
    acc[12] = fmaf(a3.x, v, acc[12]); acc[13] = fmaf(a3.y, v, acc[13]);
    acc[14] = fmaf(a3.z, v, acc[14]); acc[15] = fmaf(a3.w, v, acc[15]);
  }

#pragma unroll
  for (int i = 0; i < 16; i++)
    unsafeAtomicAdd(ctx + (size_t)(b * kQ + q0 + i) * kH + h, acc[i]);
}

extern "C" void kernel_launch(void* const* d_in, const int* in_sizes, int n_in,
                              void* d_out, int out_size, void* d_ws,
                              size_t ws_size, hipStream_t stream) {
  const float* query = (const float*)d_in[0];
  const float* key_  = (const float*)d_in[1];
  const float* value = (const float*)d_in[2];
  const float* Wq    = (const float*)d_in[3];
  const float* bq    = (const float*)d_in[4];
  const float* Wk    = (const float*)d_in[5];
  const float* bk    = (const float*)d_in[6];
  const float* we    = (const float*)d_in[7];
  // be (d_in[8]) cancels in softmax.

  float* ctx  = (float*)d_out;                         // [256*512]
  float* wout = (float*)d_out + (size_t)kB * kQ * kH;  // [256*1024]

  float* qp = (float*)d_ws;                  // 512 KB
  float* kp = qp + (size_t)kB * kQ * kH;     // 8.4 MB

  init_kernel<<<(kKpF4 + kQpF4 + kCtxF4 + 255) / 256, 256, 0, stream>>>(
      bk, bq, kp, qp, ctx);
  proj_dual<<<dim3(8, 68, 2), 256, 0, stream>>>(key_, Wk, kp, query, Wq, qp);
  score_kernel<<<1024, 256, 0, stream>>>(qp, kp, we, wout);
  softmax_kernel<<<kB * kQ, 256, 0, stream>>>(wout);
  context_kernel<<<512, 256, 0, stream>>>(wout, value, ctx);
}

// Round 6
// 187.956 us; speedup vs baseline: 1.2291x; 1.2291x over previous
//
#include <hip/hip_runtime.h>

// SoftAttention: B=4, Q=64, S=1024, H=512, fp32.
// out = [context (B*Q*H)] ++ [weights (B*Q*S)]
// ws: qp [256*512] at 0; kp [4096*512] at +512KB; context partials alias kp
// (kp is dead after score_kernel).
// qp/kp hold 2*(X@W+b); score uses exp(2*(q+k)); be cancels in softmax.
// NOTE (r5 lesson): global fp32 atomics => memory-side RMW (84MB HBM writes),
// never accumulate partials via atomicAdd on this chip.

constexpr int kB = 4;
constexpr int kQ = 64;
constexpr int kS = 1024;
constexpr int kH = 512;

// ---------------------------------------------------------------------------
// Projection: Y = 2*(X[M,512] @ W[512,512] + bias).
// 32x64 tile, 256 thr, 2x4 acc/thread, K-chunks of 32 double-buffered.
// grid = (8 col-tiles, 136 row-tiles: 128 kp + 8 qp) = 1088 blocks (~4.25/CU).
// LDS = 2*(32*36 + 32*68)*4 = 26.6 KB.
// ---------------------------------------------------------------------------
constexpr int kAStride = 36;  // 32 + 4
constexpr int kBStride = 68;  // 64 + 4

__global__ __launch_bounds__(256, 4) void proj_dual(
    const float* __restrict__ Xk, const float* __restrict__ Wk,
    const float* __restrict__ bk, float* __restrict__ Yk,
    const float* __restrict__ Xq, const float* __restrict__ Wq,
    const float* __restrict__ bq, float* __restrict__ Yq) {
  __shared__ __align__(16) float As[2][32 * kAStride];  // [k][row]
  __shared__ __align__(16) float Bs[2][32 * kBStride];  // [k][col]
  const int t = threadIdx.x;
  const int ct = blockIdx.x;  // 0..7
  int rt = blockIdx.y;        // 0..135
  const float *X, *W, *bias;
  float* Y;
  if (rt < 128) {
    X = Xk + (size_t)rt * 32 * kH; W = Wk; bias = bk; Y = Yk + (size_t)rt * 32 * kH;
  } else {
    rt -= 128;
    X = Xq + (size_t)rt * 32 * kH; W = Wq; bias = bq; Y = Yq + (size_t)rt * 32 * kH;
  }

  // A staging: row = t&31, k0 = (t>>5)*4, one float4/thread (transposed store)
  const int a_row = t & 31;
  const int a_k0 = (t >> 5) * 4;
  // B staging: pass p in {0,1}: k = p*16 + (t>>4), c = (t&15)*4
  const int b_kl = t >> 4;
  const int b_c = (t & 15) * 4;
  const int cbase = ct * 64;
  // Compute mapping: 2 rows x 4 cols per thread
  const int r0 = (t >> 4) * 2;
  const int c0 = (t & 15) * 4;

  float4 pa;
  float4 pb[2];

  auto gload = [&](int kb) {
    pa = *(const float4*)(X + (size_t)a_row * kH + kb + a_k0);
#pragma unroll
    for (int p = 0; p < 2; p++)
      pb[p] = *(const float4*)(W + (size_t)(kb + p * 16 + b_kl) * kH + cbase + b_c);
  };

  auto lwrite = [&](int buf) {
    float* a = As[buf];
    a[(a_k0 + 0) * kAStride + a_row] = pa.x;
    a[(a_k0 + 1) * kAStride + a_row] = pa.y;
    a[(a_k0 + 2) * kAStride + a_row] = pa.z;
    a[(a_k0 + 3) * kAStride + a_row] = pa.w;
    float* b = Bs[buf];
#pragma unroll
    for (int p = 0; p < 2; p++)
      *(float4*)(b + (p * 16 + b_kl) * kBStride + b_c) = pb[p];
  };

  float4 acc0 = {0,0,0,0}, acc1 = {0,0,0,0};

  gload(0);
  lwrite(0);
  __syncthreads();

  for (int kc = 0; kc < 16; kc++) {
    if (kc < 15) gload((kc + 1) * 32);

    const float* a = As[kc & 1];
    const float* b = Bs[kc & 1];
#pragma unroll 8
    for (int kk = 0; kk < 32; kk++) {
      float2 av = *(const float2*)(a + kk * kAStride + r0);
      float4 bv = *(const float4*)(b + kk * kBStride + c0);
      acc0.x = fmaf(av.x, bv.x, acc0.x); acc0.y = fmaf(av.x, bv.y, acc0.y);
      acc0.z = fmaf(av.x, bv.z, acc0.z); acc0.w = fmaf(av.x, bv.w, acc0.w);
      acc1.x = fmaf(av.y, bv.x, acc1.x); acc1.y = fmaf(av.y, bv.y, acc1.y);
      acc1.z = fmaf(av.y, bv.z, acc1.z); acc1.w = fmaf(av.y, bv.w, acc1.w);
    }

    if (kc < 15) {
      __syncthreads();
      lwrite((kc + 1) & 1);
      __syncthreads();
    }
  }

  // Y = 2*(acc + bias)
  float4 bv = *(const float4*)(bias + cbase + c0);
  float* yp = Y + (size_t)r0 * kH + cbase + c0;
  float4 o;
  o.x = 2.f*(acc0.x+bv.x); o.y = 2.f*(acc0.y+bv.y); o.z = 2.f*(acc0.z+bv.z); o.w = 2.f*(acc0.w+bv.w);
  *(float4*)(yp + 0 * kH) = o;
  o.x = 2.f*(acc1.x+bv.x); o.y = 2.f*(acc1.y+bv.y); o.z = 2.f*(acc1.z+bv.z); o.w = 2.f*(acc1.w+bv.w);
  *(float4*)(yp + 1 * kH) = o;
}

// ---------------------------------------------------------------------------
// Scores (raw) -> sout[bq][s].  tanh(x) = 1 - 2*rcp(1+exp(2x));
// sum we*tanh = sum_we + sum (-2*we)*rcp(1+exp(2q+2k)).
// grid = 2048 (b x 16 q-tiles x 32 s-chunks), 256 thr = 4 waves, 8 s/wave.
// 8 waves/SIMD for latency hiding; next k-row prefetched in registers.
// ---------------------------------------------------------------------------
__global__ __launch_bounds__(256) void score_kernel(
    const float* __restrict__ qp, const float* __restrict__ kp,
    const float* __restrict__ we, float* __restrict__ sout) {
  const int bx = blockIdx.x;
  const int b = bx >> 9, qt = (bx >> 5) & 15, st = bx & 31;
  const int t = threadIdx.x, wave = t >> 6, lane = t & 63;

  const float4* we4 = (const float4*)(we + lane * 8);
  float4 w0 = we4[0], w1 = we4[1];
  float wsum = w0.x + w0.y + w0.z + w0.w + w1.x + w1.y + w1.z + w1.w;
#pragma unroll
  for (int off = 32; off; off >>= 1) wsum += __shfl_xor(wsum, off);
  w0.x *= -2.f; w0.y *= -2.f; w0.z *= -2.f; w0.w *= -2.f;
  w1.x *= -2.f; w1.y *= -2.f; w1.z *= -2.f; w1.w *= -2.f;

  const int q0 = qt * 4;
  float4 qv[4][2];
#pragma unroll
  for (int i = 0; i < 4; i++) {
    const float4* q4 = (const float4*)(qp + (size_t)(b * kQ + q0 + i) * kH + lane * 8);
    qv[i][0] = q4[0]; qv[i][1] = q4[1];
  }

  const int sbase = st * 32 + wave * 8;
  const float* kbase = kp + ((size_t)b * kS + sbase) * kH + lane * 8;

  float4 k0 = *(const float4*)(kbase);
  float4 k1 = *(const float4*)(kbase + 4);

  for (int si = 0; si < 8; si++) {
    float4 n0, n1;
    if (si < 7) {
      const float* np = kbase + (size_t)(si + 1) * kH;
      n0 = *(const float4*)(np);
      n1 = *(const float4*)(np + 4);
    }
    float a[4];
#pragma unroll
    for (int i = 0; i < 4; i++) {
      float acc = 0.f, e;
      e = __expf(qv[i][0].x + k0.x); acc = fmaf(w0.x, __builtin_amdgcn_rcpf(1.f + e), acc);
      e = __expf(qv[i][0].y + k0.y); acc = fmaf(w0.y, __builtin_amdgcn_rcpf(1.f + e), acc);
      e = __expf(qv[i][0].z + k0.z); acc = fmaf(w0.z, __builtin_amdgcn_rcpf(1.f + e), acc);
      e = __expf(qv[i][0].w + k0.w); acc = fmaf(w0.w, __builtin_amdgcn_rcpf(1.f + e), acc);
      e = __expf(qv[i][1].x + k1.x); acc = fmaf(w1.x, __builtin_amdgcn_rcpf(1.f + e), acc);
      e = __expf(qv[i][1].y + k1.y); acc = fmaf(w1.y, __builtin_amdgcn_rcpf(1.f + e), acc);
      e = __expf(qv[i][1].z + k1.z); acc = fmaf(w1.z, __builtin_amdgcn_rcpf(1.f + e), acc);
      e = __expf(qv[i][1].w + k1.w); acc = fmaf(w1.w, __builtin_amdgcn_rcpf(1.f + e), acc);
      a[i] = acc;
    }
#pragma unroll
    for (int i = 0; i < 4; i++) {
#pragma unroll
      for (int off = 32; off; off >>= 1) a[i] += __shfl_xor(a[i], off);
    }
    if (lane == 0) {
      const int s = sbase + si;
#pragma unroll
      for (int i = 0; i < 4; i++)
        sout[(size_t)(b * kQ + q0 + i) * kS + s] = a[i] + wsum;
    }
    k0 = n0; k1 = n1;
  }
}

// ---------------------------------------------------------------------------
// Softmax in place on wout rows of 1024.  grid = 256 rows, 256 thr.
// ---------------------------------------------------------------------------
__global__ __launch_bounds__(256) void softmax_kernel(float* __restrict__ wout) {
  __shared__ float redm[4];
  __shared__ float reds[4];
  const int row = blockIdx.x;
  const int t = threadIdx.x, wave = t >> 6, lane = t & 63;
  float4* rp = (float4*)(wout + (size_t)row * kS);
  float4 v = rp[t];

  float m = fmaxf(fmaxf(v.x, v.y), fmaxf(v.z, v.w));
#pragma unroll
  for (int off = 32; off; off >>= 1) m = fmaxf(m, __shfl_xor(m, off));
  if (lane == 0) redm[wave] = m;
  __syncthreads();
  m = fmaxf(fmaxf(redm[0], redm[1]), fmaxf(redm[2], redm[3]));

  float4 e;
  e.x = __expf(v.x - m); e.y = __expf(v.y - m);
  e.z = __expf(v.z - m); e.w = __expf(v.w - m);
  float sum = e.x + e.y + e.z + e.w;
#pragma unroll
  for (int off = 32; off; off >>= 1) sum += __shfl_xor(sum, off);
  if (lane == 0) reds[wave] = sum;
  __syncthreads();
  sum = reds[0] + reds[1] + reds[2] + reds[3];
  float inv = 1.f / sum;
  e.x *= inv; e.y *= inv; e.z *= inv; e.w *= inv;
  rp[t] = e;
}

// ---------------------------------------------------------------------------
// Context partials: part[sc][bq][h] = sum_{s in 64-chunk} w[bq][s]*value[b][s][h]
// grid = 512 (b x 2 h-chunks x 4 q-chunks x 16 s-chunks), 256 thr.
// ---------------------------------------------------------------------------
__global__ __launch_bounds__(256) void context_kernel(
    const float* __restrict__ wout, const float* __restrict__ value,
    float* __restrict__ part) {
  __shared__ __align__(16) float wt[64][16];
  const int bx = blockIdx.x;
  const int sc = bx & 15, qc = (bx >> 4) & 3, hc = (bx >> 6) & 1, b = bx >> 7;
  const int t = threadIdx.x;
  const int s0 = sc * 64, q0 = qc * 16;

  {  // load + transpose weights tile [16 q][64 s] -> wt[s][q]
    const int q_l = t & 15;
    const int sseg = (t >> 4) * 4;
    float4 u = *(const float4*)(wout + (size_t)(b * kQ + q0 + q_l) * kS + s0 + sseg);
    wt[sseg + 0][q_l] = u.x; wt[sseg + 1][q_l] = u.y;
    wt[sseg + 2][q_l] = u.z; wt[sseg + 3][q_l] = u.w;
  }
  __syncthreads();

  const int h = hc * 256 + t;
  const float* vb = value + ((size_t)b * kS + s0) * kH + h;
  float acc[16];
#pragma unroll
  for (int i = 0; i < 16; i++) acc[i] = 0.f;

#pragma unroll 8
  for (int s = 0; s < 64; s++) {
    float v = vb[(size_t)s * kH];
    const float4* wrow = (const float4*)&wt[s][0];
    float4 a0 = wrow[0], a1 = wrow[1], a2 = wrow[2], a3 = wrow[3];
    acc[0]  = fmaf(a0.x, v, acc[0]);  acc[1]  = fmaf(a0.y, v, acc[1]);
    acc[2]  = fmaf(a0.z, v, acc[2]);  acc[3]  = fmaf(a0.w, v, acc[3]);
    acc[4]  = fmaf(a1.x, v, acc[4]);  acc[5]  = fmaf(a1.y, v, acc[5]);
    acc[6]  = fmaf(a1.z, v, acc[6]);  acc[7]  = fmaf(a1.w, v, acc[7]);
    acc[8]  = fmaf(a2.x, v, acc[8]);  acc[9]  = fmaf(a2.y, v, acc[9]);
    acc[10] = fmaf(a2.z, v, acc[10]); acc[11] = fmaf(a2.w, v, acc[11]);
    acc[12] = fmaf(a3.x, v, acc[12]); acc[13] = fmaf(a3.y, v, acc[13]);
    acc[14] = fmaf(a3.z, v, acc[14]); acc[15] = fmaf(a3.w, v, acc[15]);
  }

  float* pp = part + (size_t)sc * kB * kQ * kH;
#pragma unroll
  for (int i = 0; i < 16; i++)
    pp[(size_t)(b * kQ + q0 + i) * kH + h] = acc[i];
}

// ctx[i] = sum over 16 s-chunk partials.  grid = 128, 256 thr.
__global__ __launch_bounds__(256) void reduce_kernel(
    const float* __restrict__ part, float* __restrict__ ctx) {
  const int i = blockIdx.x * 256 + threadIdx.x;  // float4 index, 32768 total
  float4 a = {0, 0, 0, 0};
#pragma unroll
  for (int p = 0; p < 16; p++) {
    float4 v = ((const float4*)(part + (size_t)p * kB * kQ * kH))[i];
    a.x += v.x; a.y += v.y; a.z += v.z; a.w += v.w;
  }
  ((float4*)ctx)[i] = a;
}

extern "C" void kernel_launch(void* const* d_in, const int* in_sizes, int n_in,
                              void* d_out, int out_size, void* d_ws,
                              size_t ws_size, hipStream_t stream) {
  const float* query = (const float*)d_in[0];
  const float* key_  = (const float*)d_in[1];
  const float* value = (const float*)d_in[2];
  const float* Wq    = (const float*)d_in[3];
  const float* bq    = (const float*)d_in[4];
  const float* Wk    = (const float*)d_in[5];
  const float* bk    = (const float*)d_in[6];
  const float* we    = (const float*)d_in[7];
  // be (d_in[8]) cancels in softmax.

  float* ctx  = (float*)d_out;                         // [256*512]
  float* wout = (float*)d_out + (size_t)kB * kQ * kH;  // [256*1024]

  float* qp   = (float*)d_ws;                          // 512 KB
  float* kp   = qp + (size_t)kB * kQ * kH;             // 8 MB
  float* part = kp;  // aliases kp (dead after score); 16*0.5 MB = 8 MB

  proj_dual<<<dim3(8, 136), 256, 0, stream>>>(key_, Wk, bk, kp, query, Wq, bq, qp);
  score_kernel<<<2048, 256, 0, stream>>>(qp, kp, we, wout);
  softmax_kernel<<<kB * kQ, 256, 0, stream>>>(wout);
  context_kernel<<<512, 256, 0, stream>>>(wout, value, part);
  reduce_kernel<<<128, 256, 0, stream>>>(part, ctx);
}